// Round 9
// baseline (1363.585 us; speedup 1.0000x reference)
//
#include <hip/hip_runtime.h>
#include <hip/hip_bf16.h>
#include <stdint.h>
#include <stddef.h>

// ---------------- problem dims (fixed by setup_inputs) ----------------
#define M_DIM 8192
#define K_DIM 4096
#define N_DIM 16384

#define BM 256
#define BN 256
#define BK 32
#define NBUF 4                  // LDS ring depth (prefetch distance 3)
#define KSTEPS (K_DIM / BK)     // 128
#define SLOT_SH (BM * BK)       // 8192 shorts = 16 KB per matrix per slot

typedef __attribute__((ext_vector_type(8))) short bf16x8;  // 8 bf16 = 4 VGPRs
typedef __attribute__((ext_vector_type(4))) float f32x4;
typedef __attribute__((ext_vector_type(4))) int   i32x4;

// fp32 -> bf16, round-to-nearest-even (inputs finite)
static __device__ __forceinline__ short f2bf(float f) {
    union { float f; uint32_t u; } v; v.f = f;
    uint32_t r = v.u + 0x7FFFu + ((v.u >> 16) & 1u);
    return (short)(r >> 16);
}

// FP4 E2M1 decode: low 3 bits magnitude code, bit 3 sign.
static __device__ __forceinline__ float e2m1(int v) {
    int e = (v >> 1) & 3;
    int m = v & 1;
    float mag = (e == 0) ? 0.5f * (float)m
                         : (float)(2 + m) * 0.25f * (float)(1 << e);
    return (v & 8) ? -mag : mag;
}

// async global->LDS, 16 bytes per lane; LDS dest is wave-uniform base + lane*16
static __device__ __forceinline__ void gload16(short* lds, const short* g) {
    __builtin_amdgcn_global_load_lds(
        (const __attribute__((address_space(1))) void*)g,
        (__attribute__((address_space(3))) void*)lds,
        16, 0, 0);
}

// ---------------- kernel 1: x fp32 -> bf16 ----------------
__global__ void cast_x_kernel(const float* __restrict__ x, short* __restrict__ xb) {
    size_t i = (size_t)blockIdx.x * 256 + threadIdx.x;   // one short8 per thread
    const float4* s = reinterpret_cast<const float4*>(x);
    float4 a = s[2 * i];
    float4 b = s[2 * i + 1];
    bf16x8 o;
    o[0] = f2bf(a.x); o[1] = f2bf(a.y); o[2] = f2bf(a.z); o[3] = f2bf(a.w);
    o[4] = f2bf(b.x); o[5] = f2bf(b.y); o[6] = f2bf(b.z); o[7] = f2bf(b.w);
    reinterpret_cast<bf16x8*>(xb)[i] = o;
}

// ---------------- kernel 2: dequant w_q -> bf16 [N, K] ----------------
__global__ void dequant_w_kernel(const int* __restrict__ wq,
                                 const float* __restrict__ wos,
                                 const float* __restrict__ wis,
                                 short* __restrict__ wb) {
    int tid = blockIdx.x * 256 + threadIdx.x;    // N*(K/16) = 4,194,304 total
    int n   = tid >> 8;                          // K/16 = 256 inner blocks per row
    int blk = tid & 255;
    float scale = wis[(n << 8) | blk] * wos[(n << 5) | (blk >> 3)];
    const i32x4* q = reinterpret_cast<const i32x4*>(wq + ((size_t)n << 11) + (blk << 3));
    i32x4 q0 = q[0], q1 = q[1];
    bf16x8 o0, o1;
#pragma unroll
    for (int j = 0; j < 4; ++j) {
        int c = q0[j];
        o0[2 * j]     = f2bf(e2m1(c & 15) * scale);         // even in-feature
        o0[2 * j + 1] = f2bf(e2m1((c >> 4) & 15) * scale);  // odd in-feature
    }
#pragma unroll
    for (int j = 0; j < 4; ++j) {
        int c = q1[j];
        o1[2 * j]     = f2bf(e2m1(c & 15) * scale);
        o1[2 * j + 1] = f2bf(e2m1((c >> 4) & 15) * scale);
    }
    bf16x8* dst = reinterpret_cast<bf16x8*>(wb) + 2 * (size_t)tid;
    dst[0] = o0;
    dst[1] = o1;
}

// ---------------- kernel 3: C[M,N] = A[M,K] * B[N,K]^T, bf16 in / fp32 out --
// R8 = R5's deep ring + R7's phase ordering:
//   256x256 tile, BK=32, 512 threads (8 waves, 2m x 4n; 128x64 C per wave).
//   4-slot LDS ring (128 KB), prefetch distance 3 K-steps (~3700 cyc slack),
//   ONE counted vmcnt(8) per K-step (12 outstanding -> drains only tile
//   tt+1's 4 oldest loads; NEVER 0 in-loop -- T4, the R7 violation fixed).
//   Per K-step 2 phases: {ds_reads + 2 gloads BEFORE barrier -> s_barrier ->
//   lgkmcnt(0) -> sched_barrier (rule #18) -> setprio(1) 16 MFMA setprio(0)
//   -> barrier}. Swizzle verified conflict-free (R4-R7: SQ_LDS_BANK_CONFLICT
//   == 0). Race audit: stage at step tt writes slot (tt+3)&3 = (tt-1)&3,
//   last read before step tt-1's closing barrier, and these gloads issue
//   after it; tile tt's landing guaranteed by step tt-1's vmcnt(8)+barrier.
//   Wrap stages (tt>=125) are dead data, race-free.
__global__ __launch_bounds__(512)
void gemm_bt_kernel(const short* __restrict__ A,
                    const short* __restrict__ B,
                    float* __restrict__ C) {
    __shared__ __align__(16) short As[NBUF * SLOT_SH];   // 64 KB
    __shared__ __align__(16) short Bs[NBUF * SLOT_SH];   // 64 KB

    // raster: each XCD owns an 8-wide n-stripe, n-fast (R3, FETCH-verified)
    int bid = blockIdx.x;
    int xcd = bid & 7;
    int idx = bid >> 3;          // 0..255
    int im  = idx >> 3;          // 0..31
    int in8 = idx & 7;           // 0..7
    int bm  = im << 8;
    int bn  = ((xcd << 3) + in8) << 8;

    int t    = threadIdx.x;
    int lane = t & 63;
    int w    = t >> 6;           // wave 0..7
    int wm   = w >> 2;           // 0..1
    int wn   = w & 3;            // 0..3
    int fr   = lane & 15;
    int fq   = lane >> 4;
    int wbase = w << 9;          // wave staging base (shorts): w * 512

    // staging: thread t covers row (t>>2) of each 128-row chunk, 16B slot t&3.
    // pre-swizzled global k-chunk = (t&3) ^ ((row>>1)&3)  (R4-verified)
    int gcol = (((t & 3) ^ ((t >> 3) & 3)) << 3);        // shorts
    const short* AgB = A + (size_t)(bm + (t >> 2)) * K_DIM + gcol;
    const short* BgB = B + (size_t)(bn + (t >> 2)) * K_DIM + gcol;

    // read-side swizzled slot (constant per lane): fq ^ ((fr>>1)&3)
    int slot = fq ^ ((fr >> 1) & 3);
    int aoff[8], boff[4];
#pragma unroll
    for (int mi = 0; mi < 8; ++mi)
        aoff[mi] = ((wm << 7) + mi * 16 + fr) * 4 + slot;
#pragma unroll
    for (int ni = 0; ni < 4; ++ni)
        boff[ni] = ((wn << 6) + ni * 16 + fr) * 4 + slot;

    f32x4 acc[8][4] = {};

    // one matrix K-step tile = 16 KB = 2 gloads (512 thr x 16 B = 8 KB each)
#define STAGE_A(slot_, kt_)                                                   \
    do {                                                                      \
        const short* _s = AgB + (size_t)(kt_) * BK;                           \
        short* _d = As + (slot_) * SLOT_SH + wbase;                           \
        gload16(_d,        _s);                                               \
        gload16(_d + 4096, _s + (size_t)128 * K_DIM);                         \
    } while (0)
#define STAGE_B(slot_, kt_)                                                   \
    do {                                                                      \
        const short* _s = BgB + (size_t)(kt_) * BK;                           \
        short* _d = Bs + (slot_) * SLOT_SH + wbase;                           \
        gload16(_d,        _s);                                               \
        gload16(_d + 4096, _s + (size_t)128 * K_DIM);                         \
    } while (0)

// phase boundary: pin reads/stage above, then barrier, then drain LDS and
// pin again so MFMA can't hoist past the wait (rule #18)
#define PHASE_GATE()                                                          \
    do {                                                                      \
        __builtin_amdgcn_sched_barrier(0);                                    \
        __builtin_amdgcn_s_barrier();                                         \
        asm volatile("s_waitcnt lgkmcnt(0)" ::: "memory");                    \
        __builtin_amdgcn_sched_barrier(0);                                    \
    } while (0)

    // prologue: stage K-steps 0..2 (12 loads), wait for tile 0 only
    STAGE_A(0, 0); STAGE_B(0, 0);
    STAGE_A(1, 1); STAGE_B(1, 1);
    STAGE_A(2, 2); STAGE_B(2, 2);
    asm volatile("s_waitcnt vmcnt(8)" ::: "memory");
    __builtin_amdgcn_s_barrier();

    for (int tt = 0; tt < KSTEPS; ++tt) {
        int c     = tt & 3;
        int pslot = (tt + 3) & 3;
        int ktn   = (tt + 3) & (KSTEPS - 1);   // dead wrap for tt >= 125
        const bf16x8* Af = reinterpret_cast<const bf16x8*>(As + c * SLOT_SH);
        const bf16x8* Bf = reinterpret_cast<const bf16x8*>(Bs + c * SLOT_SH);

        bf16x8 av[4], aw[4], bv[4];

        // ---- ph0: reads B + A m0-3; stage A(tt+3); gate; MFMA Q0
#pragma unroll
        for (int ni = 0; ni < 4; ++ni) bv[ni] = Bf[boff[ni]];
#pragma unroll
        for (int mi = 0; mi < 4; ++mi) av[mi] = Af[aoff[mi]];
        STAGE_A(pslot, ktn);
        PHASE_GATE();
        __builtin_amdgcn_s_setprio(1);
#pragma unroll
        for (int mi = 0; mi < 4; ++mi)
#pragma unroll
            for (int ni = 0; ni < 4; ++ni)
                acc[mi][ni] = __builtin_amdgcn_mfma_f32_16x16x32_bf16(
                    av[mi], bv[ni], acc[mi][ni], 0, 0, 0);
        __builtin_amdgcn_s_setprio(0);
        __builtin_amdgcn_s_barrier();

        // ---- ph1: reads A m4-7; stage B(tt+3); gate; MFMA Q1 (bv reused);
        //            counted vmcnt(8); closing barrier
#pragma unroll
        for (int mi = 0; mi < 4; ++mi) aw[mi] = Af[aoff[mi + 4]];
        STAGE_B(pslot, ktn);
        PHASE_GATE();
        __builtin_amdgcn_s_setprio(1);
#pragma unroll
        for (int mi = 0; mi < 4; ++mi)
#pragma unroll
            for (int ni = 0; ni < 4; ++ni)
                acc[mi + 4][ni] = __builtin_amdgcn_mfma_f32_16x16x32_bf16(
                    aw[mi], bv[ni], acc[mi + 4][ni], 0, 0, 0);
        __builtin_amdgcn_s_setprio(0);
        // 12 outstanding (tiles tt+1,tt+2,tt+3): wait the 4 oldest (tile
        // tt+1) only -- counted, never 0 (T4). Cross-wave visibility via
        // the closing barrier; next ph0 reads tile tt+1.
        asm volatile("s_waitcnt vmcnt(8)" ::: "memory");
        __builtin_amdgcn_s_barrier();
    }
#undef PHASE_GATE
#undef STAGE_A
#undef STAGE_B

    // epilogue: C/D layout col = lane&15, row = (lane>>4)*4 + reg
#pragma unroll
    for (int mi = 0; mi < 8; ++mi) {
#pragma unroll
        for (int j = 0; j < 4; ++j) {
            size_t row = (size_t)(bm + (wm << 7) + mi * 16 + fq * 4 + j);
            float* Crow = C + row * N_DIM + (bn + (wn << 6) + fr);
#pragma unroll
            for (int ni = 0; ni < 4; ++ni)
                Crow[ni * 16] = acc[mi][ni][j];
        }
    }
}

// ---------------- launch ----------------
extern "C" void kernel_launch(void* const* d_in, const int* in_sizes, int n_in,
                              void* d_out, int out_size, void* d_ws, size_t ws_size,
                              hipStream_t stream) {
    const float* x   = (const float*)d_in[0];
    const int*   wq  = (const int*)d_in[1];
    const float* wos = (const float*)d_in[2];
    const float* wis = (const float*)d_in[3];
    float* out = (float*)d_out;

    short* xb = (short*)d_ws;                                        // 64 MB
    short* wb = (short*)((char*)d_ws + (size_t)M_DIM * K_DIM * 2);   // 128 MB

    cast_x_kernel<<<(M_DIM * (size_t)K_DIM / 8) / 256, 256, 0, stream>>>(x, xb);
    dequant_w_kernel<<<(N_DIM * (size_t)K_DIM / 16) / 256, 256, 0, stream>>>(wq, wos, wis, wb);
    gemm_bt_kernel<<<(M_DIM / BM) * (N_DIM / BN), 512, 0, stream>>>(xb, wb, out);
}